// Round 3
// baseline (292.728 us; speedup 1.0000x reference)
//
#include <hip/hip_runtime.h>

#define B_TOK   8192
#define D_IN    1024
#define D_OUT   1024
#define NEXP    8
#define RH      128
#define MAXTILES 136
#define MAXSLOTS (MAXTILES*128)

typedef __attribute__((ext_vector_type(8))) short v8s;
typedef __attribute__((ext_vector_type(8))) unsigned short v8u;
typedef __attribute__((ext_vector_type(4))) float v4f;

__device__ __forceinline__ unsigned short f2bf(float f){
  unsigned int u = __float_as_uint(f);
  u += 0x7fffu + ((u >> 16) & 1u);
  return (unsigned short)(u >> 16);
}
__device__ __forceinline__ float bf2f(unsigned short s){
  return __uint_as_float(((unsigned int)s) << 16);
}
// async global->LDS, 16B per lane. LDS dest must be wave-uniform base (+lane*16 implicit).
__device__ __forceinline__ void gload16(const void* g, void* l){
  __builtin_amdgcn_global_load_lds(
      (const __attribute__((address_space(1))) unsigned int*)g,
      (__attribute__((address_space(3))) unsigned int*)l, 16, 0, 0);
}

// ---------------- kernel 1: ew [e][k][n] fp32 -> ewT [e][n][k] bf16 ----------------
__global__ __launch_bounds__(256) void k_cvt_ew(const float* __restrict__ ew,
                                                unsigned short* __restrict__ ewT){
  __shared__ float tile[32][33];
  int tx = threadIdx.x, ty = threadIdx.y;
  int n0 = blockIdx.x*32, k0 = blockIdx.y*32, e = blockIdx.z;
  size_t ebase = (size_t)e << 20;                       // 1024*1024
  #pragma unroll
  for (int i=0;i<4;i++){
    int kl = ty*4+i;
    tile[kl][tx] = ew[ebase + (size_t)(k0+kl)*1024 + n0 + tx];
  }
  __syncthreads();
  #pragma unroll
  for (int i=0;i<4;i++){
    int nl = ty*4+i;
    ewT[ebase + (size_t)(n0+nl)*1024 + (k0 + tx)] = f2bf(tile[tx][nl]);
  }
}

// ---------------- kernel 2: router (fp32) + fused x->bf16 emission ----------------
// grid 256 blocks x 128 threads; 32 tokens per block. Router MUST stay fp32:
// bf16 logits flip top-k selection for ~1e-3 of tokens -> O(0.2) absmax fail.
// Each block streams its 32 token rows exactly once -> also emits xbf (disjoint
// writes, fully rewritten each call => poison-safe).
__global__ __launch_bounds__(128) void k_router(
    const float* __restrict__ x,  const float* __restrict__ rw1,
    const float* __restrict__ rb1,const float* __restrict__ rw2,
    const float* __restrict__ rb2,
    unsigned short* __restrict__ xbf,
    int2* __restrict__ tok_ids, float2* __restrict__ tok_w)
{
  __shared__ float xs [64*32];      // [k][m]
  __shared__ float ws1[64*128];     // [k][rh]
  __shared__ float hs [32*129];     // padded stride 129 -> conflict-free phase 2
  __shared__ float rw2s[RH*NEXP];
  int tid = threadIdx.x;
  int tx = tid & 15, ty = tid >> 4;           // tx: rh groups, ty: token groups (4 tok each)
  int tok0 = blockIdx.x * 32;
  // stage rw2 (RH*E = 1024 floats)
  {
    float4 v0 = *(const float4*)(rw2 + tid*8);
    float4 v1 = *(const float4*)(rw2 + tid*8 + 4);
    *(float4*)(rw2s + tid*8)     = v0;
    *(float4*)(rw2s + tid*8 + 4) = v1;
  }
  float acc[4][8];
  #pragma unroll
  for (int i=0;i<4;i++)
    #pragma unroll
    for (int j=0;j<8;j++) acc[i][j]=0.f;

  for (int k0=0;k0<D_IN;k0+=64){
    { // stage xs transposed [k][m] + emit bf16 copy of the 16 floats handled
      int m = tid & 31, cb4 = tid >> 5;
      union { v8u v[2]; unsigned short s[16]; } ub;
      #pragma unroll
      for (int i=0;i<4;i++){
        int chunk = cb4*4 + i;   // 0..15 (float4 chunks of the 64-wide k slab)
        float4 v = *(const float4*)(x + (size_t)(tok0+m)*D_IN + k0 + chunk*4);
        xs[(chunk*4+0)*32 + m] = v.x;
        xs[(chunk*4+1)*32 + m] = v.y;
        xs[(chunk*4+2)*32 + m] = v.z;
        xs[(chunk*4+3)*32 + m] = v.w;
        ub.s[i*4+0]=f2bf(v.x); ub.s[i*4+1]=f2bf(v.y);
        ub.s[i*4+2]=f2bf(v.z); ub.s[i*4+3]=f2bf(v.w);
      }
      unsigned short* xo = xbf + (size_t)(tok0+m)*D_IN + k0 + cb4*16;
      *(v8u*)(xo)     = ub.v[0];
      *(v8u*)(xo + 8) = ub.v[1];
    }
    #pragma unroll
    for (int i=0;i<16;i++){ // stage ws1 [64][128]
      int idx = tid + 128*i;
      int row = idx >> 5, c4 = (idx & 31)*4;
      *(float4*)(ws1 + row*128 + c4) = *(const float4*)(rw1 + (size_t)(k0+row)*RH + c4);
    }
    __syncthreads();
    #pragma unroll 8
    for (int k=0;k<64;k++){
      float4 a  = *(float4*)(xs  + k*32 + ty*4);
      float4 b0 = *(float4*)(ws1 + k*128 + tx*4);        // rh cols tx*4..+3
      float4 b1 = *(float4*)(ws1 + k*128 + 64 + tx*4);   // rh cols 64+tx*4..+3
      float av[4] = {a.x,a.y,a.z,a.w};
      float bv[8] = {b0.x,b0.y,b0.z,b0.w,b1.x,b1.y,b1.z,b1.w};
      #pragma unroll
      for (int i=0;i<4;i++)
        #pragma unroll
        for (int j=0;j<8;j++) acc[i][j] += av[i]*bv[j];
    }
    __syncthreads();
  }
  // h = tanh(acc + rb1) -> hs
  #pragma unroll
  for (int i=0;i<4;i++){
    int m = ty*4+i;
    #pragma unroll
    for (int j=0;j<4;j++){
      hs[m*129 + tx*4 + j]      = tanhf(acc[i][j]   + rb1[tx*4+j]);
      hs[m*129 + 64 + tx*4 + j] = tanhf(acc[i][4+j] + rb1[64+tx*4+j]);
    }
  }
  __syncthreads();
  if (tid < 32){
    int t = tid;
    float l[NEXP];
    #pragma unroll
    for (int e=0;e<NEXP;e++) l[e] = rb2[e];
    for (int r=0;r<RH;r++){
      float h = hs[t*129 + r];
      #pragma unroll
      for (int e=0;e<NEXP;e++) l[e] += h * rw2s[r*8 + e];
    }
    float mx = l[0];
    #pragma unroll
    for (int e=1;e<NEXP;e++) mx = fmaxf(mx, l[e]);
    float p[NEXP], s = 0.f;
    #pragma unroll
    for (int e=0;e<NEXP;e++){ p[e] = expf(l[e]-mx); s += p[e]; }
    float inv = 1.f/s;
    #pragma unroll
    for (int e=0;e<NEXP;e++) p[e] *= inv;
    // stable top-2 (first index wins ties) == jax.lax.top_k
    int bi = 0; float bv = p[0]; int si = -1; float sv = -1.f;
    #pragma unroll
    for (int e=1;e<NEXP;e++){
      if (p[e] > bv){ sv = bv; si = bi; bv = p[e]; bi = e; }
      else if (p[e] > sv){ sv = p[e]; si = e; }
    }
    // nws = softmax([bv, sv]) (softmax over the top-k prob VALUES, per reference)
    float e1 = expf(sv - bv);
    float n0 = 1.f/(1.f + e1);
    float n1 = 1.f - n0;
    tok_ids[tok0 + t] = make_int2(bi, si);
    tok_w [tok0 + t] = make_float2(n0, n1);
  }
}

// ---------------- kernel 3: dispatch (single block) ----------------
__global__ __launch_bounds__(1024) void k_dispatch(
    const int2* __restrict__ tok_ids, const float2* __restrict__ tok_w,
    int* __restrict__ atok, float* __restrict__ aw,
    int* __restrict__ slotA, int* __restrict__ slotB,
    int2* __restrict__ ttab, int* __restrict__ ntiles)
{
  __shared__ int cnt[NEXP], base[NEXP], cur[NEXP];
  __shared__ int tot;
  int tid = threadIdx.x;
  if (tid < NEXP){ cnt[tid]=0; cur[tid]=0; }
  __syncthreads();
  for (int t=tid; t<B_TOK; t+=1024){
    int2 e = tok_ids[t];
    atomicAdd(&cnt[e.x],1);
    atomicAdd(&cnt[e.y],1);
  }
  __syncthreads();
  if (tid==0){
    int b=0, tt=0;
    for (int e=0;e<NEXP;e++){
      base[e]=b;
      int nt = (cnt[e]+127)>>7;
      for (int i=0;i<nt;i++) ttab[tt++] = make_int2(e, b + i*128);
      b += nt*128;
    }
    tot = b; *ntiles = tt;
  }
  __syncthreads();
  int tt_ = tot;
  for (int s=tid; s<tt_; s+=1024){ atok[s]=0; aw[s]=0.f; }  // padding: token 0, weight 0
  __syncthreads();
  for (int t=tid; t<B_TOK; t+=1024){
    int2 e = tok_ids[t]; float2 w = tok_w[t];
    int sA = base[e.x] + atomicAdd(&cur[e.x],1);
    atok[sA]=t; aw[sA]=w.x; slotA[t]=sA;
    int sB = base[e.y] + atomicAdd(&cur[e.y],1);
    atok[sB]=t; aw[sB]=w.y; slotB[t]=sB;
  }
}

// ---------------- kernel 4: grouped GEMM (m97 structure, gathered A rows) ----------------
// grid (MAXTILES, 8), block 256 (4 waves, 2x2), tile 128x128, BK=64
__global__ __launch_bounds__(256) void k_gemm(
    const unsigned short* __restrict__ xbf, const unsigned short* __restrict__ ewT,
    const float* __restrict__ eb,
    const int* __restrict__ atok, const float* __restrict__ aw,
    const int2* __restrict__ ttab, const int* __restrict__ ntiles,
    unsigned short* __restrict__ Y)
{
  if ((int)blockIdx.x >= *ntiles) return;   // beyond-ntiles blocks never touch poisoned ttab
  __shared__ __align__(16) unsigned short As[128*64];
  __shared__ __align__(16) unsigned short Bs[128*64];
  __shared__ int   tokS[128];
  __shared__ float wS[128];
  int tid = threadIdx.x;
  int lane = tid & 63, wid = tid >> 6;
  int2 tt = ttab[blockIdx.x];
  int e = tt.x, slot0 = tt.y;
  int ncol0 = blockIdx.y * 128;
  if (tid < 128){ tokS[tid] = atok[slot0 + tid]; wS[tid] = aw[slot0 + tid]; }
  __syncthreads();
  int rsub = wid*8 + (lane >> 3);          // row-within-32 for each staging issue
  int cbyte = (lane & 7) * 16;             // 16B column chunk within 128B row
  const char* xB    = (const char*)xbf;
  const char* eBase = (const char*)ewT + ((size_t)e << 21);  // e * 1024*1024*2B
  const char* srcA[4]; const char* srcB[4];
  #pragma unroll
  for (int i=0;i<4;i++){
    srcA[i] = xB    + ((size_t)tokS[i*32 + rsub] << 11) + cbyte;         // token row, 2KB stride
    srcB[i] = eBase + ((size_t)(ncol0 + i*32 + rsub) << 11) + cbyte;     // n row of ewT
  }
  v4f zero = {0.f,0.f,0.f,0.f};
  v4f acc[4][4];
  #pragma unroll
  for (int mi=0;mi<4;mi++)
    #pragma unroll
    for (int ni=0;ni<4;ni++) acc[mi][ni] = zero;
  int wr = wid >> 1, wc = wid & 1;
  int fr = lane & 15, fq = lane >> 4;
  unsigned Abase = (unsigned)((wr*64 + fr)*64 + fq*8);
  unsigned Bbase = (unsigned)((wc*64 + fr)*64 + fq*8);

  for (int kt=0; kt<16; ++kt){
    int koff = kt*128;                     // bytes: 64 bf16 per K-chunk
    #pragma unroll
    for (int i=0;i<4;i++)
      gload16(srcA[i] + koff, (char*)As + (i*32 + wid*8)*128);
    #pragma unroll
    for (int i=0;i<4;i++)
      gload16(srcB[i] + koff, (char*)Bs + (i*32 + wid*8)*128);
    __syncthreads();                       // drains vmcnt -> staged data visible
    #pragma unroll
    for (int kk=0;kk<2;kk++){
      v8s a[4], b[4];
      #pragma unroll
      for (int mi=0;mi<4;mi++) a[mi] = *(const v8s*)(As + Abase + mi*16*64 + kk*32);
      #pragma unroll
      for (int ni=0;ni<4;ni++) b[ni] = *(const v8s*)(Bs + Bbase + ni*16*64 + kk*32);
      #pragma unroll
      for (int mi=0;mi<4;mi++)
        #pragma unroll
        for (int ni=0;ni<4;ni++)
          acc[mi][ni] = __builtin_amdgcn_mfma_f32_16x16x32_bf16(a[mi], b[ni], acc[mi][ni], 0, 0, 0);
    }
    __syncthreads();                       // all waves done reading before next stage
  }
  // epilogue: Y[slot] = bf16( w * (acc + eb[e]) )
  #pragma unroll
  for (int ni=0;ni<4;ni++){
    int cg = ncol0 + wc*64 + ni*16 + fr;
    float ebv = eb[e*D_OUT + cg];
    #pragma unroll
    for (int mi=0;mi<4;mi++){
      int rb0 = wr*64 + mi*16 + fq*4;
      #pragma unroll
      for (int q=0;q<4;q++){
        int r = rb0 + q;
        float v = wS[r] * (acc[mi][ni][q] + ebv);
        Y[(size_t)(slot0 + r)*D_OUT + cg] = f2bf(v);
      }
    }
  }
}

// ---------------- kernel 5: combine out[t] = Y[slotA[t]] + Y[slotB[t]] ----------------
__global__ __launch_bounds__(256) void k_combine(
    const unsigned short* __restrict__ Y,
    const int* __restrict__ slotA, const int* __restrict__ slotB,
    float* __restrict__ out)
{
  int gid = blockIdx.x*256 + threadIdx.x;   // 1M threads, 8 cols each
  int t = gid >> 7;
  int c = (gid & 127) << 3;
  v8u a = *(const v8u*)(Y + (size_t)slotA[t]*D_OUT + c);
  v8u b = *(const v8u*)(Y + (size_t)slotB[t]*D_OUT + c);
  float4 o0, o1;
  o0.x = bf2f(a[0]) + bf2f(b[0]);
  o0.y = bf2f(a[1]) + bf2f(b[1]);
  o0.z = bf2f(a[2]) + bf2f(b[2]);
  o0.w = bf2f(a[3]) + bf2f(b[3]);
  o1.x = bf2f(a[4]) + bf2f(b[4]);
  o1.y = bf2f(a[5]) + bf2f(b[5]);
  o1.z = bf2f(a[6]) + bf2f(b[6]);
  o1.w = bf2f(a[7]) + bf2f(b[7]);
  *(float4*)(out + (size_t)t*D_OUT + c)     = o0;
  *(float4*)(out + (size_t)t*D_OUT + c + 4) = o1;
}

// ---------------- launch ----------------
extern "C" void kernel_launch(void* const* d_in, const int* in_sizes, int n_in,
                              void* d_out, int out_size, void* d_ws, size_t ws_size,
                              hipStream_t stream)
{
  const float* x   = (const float*)d_in[0];
  const float* rw1 = (const float*)d_in[1];
  const float* rb1 = (const float*)d_in[2];
  const float* rw2 = (const float*)d_in[3];
  const float* rb2 = (const float*)d_in[4];
  const float* ew  = (const float*)d_in[5];
  const float* eb  = (const float*)d_in[6];
  float* out = (float*)d_out;

  char* ws = (char*)d_ws;
  size_t o = 0;
  auto alloc = [&](size_t bytes)->char*{
    char* p = ws + o; o = (o + bytes + 255) & ~(size_t)255; return p;
  };
  unsigned short* xbf = (unsigned short*)alloc((size_t)B_TOK*D_IN*2);
  unsigned short* ewT = (unsigned short*)alloc((size_t)NEXP*D_IN*D_OUT*2);
  unsigned short* Y   = (unsigned short*)alloc((size_t)MAXSLOTS*D_OUT*2);
  int2*   tok_ids = (int2*)  alloc(B_TOK*sizeof(int2));
  float2* tok_w   = (float2*)alloc(B_TOK*sizeof(float2));
  int*    atok    = (int*)   alloc(MAXSLOTS*4);
  float*  aw      = (float*) alloc(MAXSLOTS*4);
  int*    slotA   = (int*)   alloc(B_TOK*4);
  int*    slotB   = (int*)   alloc(B_TOK*4);
  int2*   ttab    = (int2*)  alloc(256*sizeof(int2));
  int*    ntil    = (int*)   alloc(256);
  if (o > ws_size) return;  // ws too small: bail (will show as validation failure)

  k_cvt_ew <<<dim3(32,32,NEXP),  dim3(32,8),  0, stream>>>(ew, ewT);
  k_router <<<dim3(256),         dim3(128),   0, stream>>>(x, rw1, rb1, rw2, rb2, xbf, tok_ids, tok_w);
  k_dispatch<<<dim3(1),          dim3(1024),  0, stream>>>(tok_ids, tok_w, atok, aw, slotA, slotB, ttab, ntil);
  k_gemm   <<<dim3(MAXTILES,8),  dim3(256),   0, stream>>>(xbf, ewT, eb, atok, aw, ttab, ntil, Y);
  k_combine<<<dim3(4096),        dim3(256),   0, stream>>>(Y, slotA, slotB, out);
}

// Round 5
// 282.666 us; speedup vs baseline: 1.0356x; 1.0356x over previous
//
#include <hip/hip_runtime.h>

#define B_TOK   8192
#define D_IN    1024
#define D_OUT   1024
#define NEXP    8
#define RH      128
#define MAXTILES 136
#define MAXSLOTS (MAXTILES*128)

typedef __attribute__((ext_vector_type(8))) short v8s;
typedef __attribute__((ext_vector_type(8))) unsigned short v8u;
typedef __attribute__((ext_vector_type(4))) unsigned short v4u;
typedef __attribute__((ext_vector_type(4))) float v4f;

__device__ __forceinline__ unsigned short f2bf(float f){
  unsigned int u = __float_as_uint(f);
  u += 0x7fffu + ((u >> 16) & 1u);
  return (unsigned short)(u >> 16);
}
__device__ __forceinline__ float bf2f(unsigned short s){
  return __uint_as_float(((unsigned int)s) << 16);
}
// async global->LDS, 16B per lane. LDS dest must be wave-uniform base (+lane*16 implicit).
__device__ __forceinline__ void gload16(const void* g, void* l){
  __builtin_amdgcn_global_load_lds(
      (const __attribute__((address_space(1))) unsigned int*)g,
      (__attribute__((address_space(3))) unsigned int*)l, 16, 0, 0);
}

// ---------------- kernel 1: ew [e][k][n] fp32 -> ewT [e][n][k] bf16 ----------------
__global__ __launch_bounds__(256) void k_cvt_ew(const float* __restrict__ ew,
                                                unsigned short* __restrict__ ewT){
  __shared__ float tile[32][33];
  int tx = threadIdx.x, ty = threadIdx.y;
  int n0 = blockIdx.x*32, k0 = blockIdx.y*32, e = blockIdx.z;
  size_t ebase = (size_t)e << 20;                       // 1024*1024
  #pragma unroll
  for (int i=0;i<4;i++){
    int kl = ty*4+i;
    tile[kl][tx] = ew[ebase + (size_t)(k0+kl)*1024 + n0 + tx];
  }
  __syncthreads();
  #pragma unroll
  for (int i=0;i<4;i++){
    int nl = ty*4+i;
    ewT[ebase + (size_t)(n0+nl)*1024 + (k0 + tx)] = f2bf(tile[tx][nl]);
  }
}

// ---------------- kernel 2: router (fp32) + fused x->bf16 emission ----------------
// Rebuilt for occupancy: 512 blocks x 256 threads, 16 tokens/block, LDS ~51KB
// (was: 256 blocks x 128 thr, 62KB LDS -> 5% occupancy, 87us latency-bound).
// Router MUST stay fp32: bf16 logits flip top-k for ~1e-3 tokens -> absmax fail.
// Lane mapping (per wave w of 4): rh0 = w*32 + (lane&15), rh1 = rh0+16,
// tokens g*4..g*4+3 where g = lane>>4. acc[4 tok][2 rh] per lane.
__global__ __launch_bounds__(256) void k_router(
    const float* __restrict__ x,  const float* __restrict__ rw1,
    const float* __restrict__ rb1,const float* __restrict__ rw2,
    const float* __restrict__ rb2,
    unsigned short* __restrict__ xbf,
    int2* __restrict__ tok_ids, float2* __restrict__ tok_w)
{
  __shared__ float xs [16*68];     // [tok][k] pad 68: b128-aligned, conflict-light
  __shared__ float ws [64*132];    // [k][rh] pad 132: scalar reads conflict-free
  __shared__ float hs [16*132];    // [tok][rh]
  __shared__ float r2s[RH*NEXP];   // [rh][e] natural rw2 layout
  __shared__ float ls [16*NEXP];
  int tid  = threadIdx.x;
  int lane = tid & 63, w = tid >> 6;
  int g    = lane >> 4;                 // token group 0..3
  int j    = lane & 15;
  int rh0  = w*32 + j, rh1 = rh0 + 16;
  int tok0 = blockIdx.x * 16;

  { // stage rw2 [128][8] = 1024 floats, 1 float4/thread
    *(float4*)(r2s + tid*4) = *(const float4*)(rw2 + tid*4);
  }
  float acc[4][2];
  #pragma unroll
  for (int i=0;i<4;i++){ acc[i][0]=0.f; acc[i][1]=0.f; }

  for (int slab=0; slab<16; ++slab){
    int k0 = slab*64;
    { // stage xs (16 tok x 64 k) + emit bf16 x. 1 float4/thread, coalesced.
      int t = tid >> 4, c4 = tid & 15;
      float4 v = *(const float4*)(x + (size_t)(tok0+t)*D_IN + k0 + c4*4);
      *(float4*)(xs + t*68 + c4*4) = v;
      v4u ub = { f2bf(v.x), f2bf(v.y), f2bf(v.z), f2bf(v.w) };
      *(v4u*)(xbf + (size_t)(tok0+t)*D_IN + k0 + c4*4) = ub;
    }
    #pragma unroll
    for (int i=0;i<8;i++){ // stage ws (64 k x 128 rh), natural, b128 coalesced
      int idx = tid + 256*i;
      int r = idx >> 5, c4 = (idx & 31)*4;
      *(float4*)(ws + r*132 + c4) = *(const float4*)(rw1 + (size_t)(k0+r)*RH + c4);
    }
    __syncthreads();
    #pragma unroll 4
    for (int k=0;k<64;k+=4){
      v4f xv[4];
      #pragma unroll
      for (int i=0;i<4;i++) xv[i] = *(v4f*)(xs + (g*4+i)*68 + k);   // broadcast in 16-lane groups
      #pragma unroll
      for (int kk=0;kk<4;kk++){
        float w0 = ws[(k+kk)*132 + rh0];
        float w1 = ws[(k+kk)*132 + rh1];
        #pragma unroll
        for (int i=0;i<4;i++){
          acc[i][0] += xv[i][kk] * w0;
          acc[i][1] += xv[i][kk] * w1;
        }
      }
    }
    __syncthreads();
  }
  // h = tanh(acc + rb1) -> hs
  {
    float b0 = rb1[rh0], b1 = rb1[rh1];
    #pragma unroll
    for (int i=0;i<4;i++){
      hs[(g*4+i)*132 + rh0] = tanhf(acc[i][0] + b0);
      hs[(g*4+i)*132 + rh1] = tanhf(acc[i][1] + b1);
    }
  }
  __syncthreads();
  // logits: 128 threads, one (token, expert) pair each
  if (tid < 16*NEXP){
    int t = tid >> 3, e = tid & 7;
    float l = rb2[e];
    #pragma unroll 4
    for (int r=0;r<RH;r++) l += hs[t*132 + r] * r2s[r*8 + e];
    ls[t*8 + e] = l;
  }
  __syncthreads();
  // softmax + stable top-2 + renorm weights: 16 threads, 8 elems each
  if (tid < 16){
    int t = tid;
    float l[NEXP];
    #pragma unroll
    for (int e=0;e<NEXP;e++) l[e] = ls[t*8 + e];
    float mx = l[0];
    #pragma unroll
    for (int e=1;e<NEXP;e++) mx = fmaxf(mx, l[e]);
    float p[NEXP], s = 0.f;
    #pragma unroll
    for (int e=0;e<NEXP;e++){ p[e] = expf(l[e]-mx); s += p[e]; }
    float inv = 1.f/s;
    #pragma unroll
    for (int e=0;e<NEXP;e++) p[e] *= inv;
    int bi = 0; float bv = p[0]; int si = -1; float sv = -1.f;
    #pragma unroll
    for (int e=1;e<NEXP;e++){
      if (p[e] > bv){ sv = bv; si = bi; bv = p[e]; bi = e; }
      else if (p[e] > sv){ sv = p[e]; si = e; }
    }
    // nws = softmax over the top-k prob VALUES, per reference
    float e1 = expf(sv - bv);
    float n0 = 1.f/(1.f + e1);
    float n1 = 1.f - n0;
    tok_ids[tok0 + t] = make_int2(bi, si);
    tok_w [tok0 + t] = make_float2(n0, n1);
  }
}

// ---------------- kernel 3: dispatch (single block) ----------------
__global__ __launch_bounds__(1024) void k_dispatch(
    const int2* __restrict__ tok_ids, const float2* __restrict__ tok_w,
    int* __restrict__ atok, float* __restrict__ aw,
    int* __restrict__ slotA, int* __restrict__ slotB,
    int2* __restrict__ ttab, int* __restrict__ ntiles)
{
  __shared__ int cnt[NEXP], base[NEXP], cur[NEXP];
  __shared__ int tot;
  int tid = threadIdx.x;
  if (tid < NEXP){ cnt[tid]=0; cur[tid]=0; }
  __syncthreads();
  for (int t=tid; t<B_TOK; t+=1024){
    int2 e = tok_ids[t];
    atomicAdd(&cnt[e.x],1);
    atomicAdd(&cnt[e.y],1);
  }
  __syncthreads();
  if (tid==0){
    int b=0, tt=0;
    for (int e=0;e<NEXP;e++){
      base[e]=b;
      int nt = (cnt[e]+127)>>7;
      for (int i=0;i<nt;i++) ttab[tt++] = make_int2(e, b + i*128);
      b += nt*128;
    }
    tot = b; *ntiles = tt;
  }
  __syncthreads();
  int tt_ = tot;
  for (int s=tid; s<tt_; s+=1024){ atok[s]=0; aw[s]=0.f; }  // padding: token 0, weight 0
  __syncthreads();
  for (int t=tid; t<B_TOK; t+=1024){
    int2 e = tok_ids[t]; float2 w = tok_w[t];
    int sA = base[e.x] + atomicAdd(&cur[e.x],1);
    atok[sA]=t; aw[sA]=w.x; slotA[t]=sA;
    int sB = base[e.y] + atomicAdd(&cur[e.y],1);
    atok[sB]=t; aw[sB]=w.y; slotB[t]=sB;
  }
}

// ---------------- kernel 4: grouped GEMM (m97 structure, gathered A rows) ----------------
// grid (MAXTILES, 8), block 256 (4 waves, 2x2), tile 128x128, BK=64
__global__ __launch_bounds__(256) void k_gemm(
    const unsigned short* __restrict__ xbf, const unsigned short* __restrict__ ewT,
    const float* __restrict__ eb,
    const int* __restrict__ atok, const float* __restrict__ aw,
    const int2* __restrict__ ttab, const int* __restrict__ ntiles,
    unsigned short* __restrict__ Y)
{
  if ((int)blockIdx.x >= *ntiles) return;   // beyond-ntiles blocks never touch poisoned ttab
  __shared__ __align__(16) unsigned short As[128*64];
  __shared__ __align__(16) unsigned short Bs[128*64];
  __shared__ int   tokS[128];
  __shared__ float wS[128];
  int tid = threadIdx.x;
  int lane = tid & 63, wid = tid >> 6;
  int2 tt = ttab[blockIdx.x];
  int e = tt.x, slot0 = tt.y;
  int ncol0 = blockIdx.y * 128;
  if (tid < 128){ tokS[tid] = atok[slot0 + tid]; wS[tid] = aw[slot0 + tid]; }
  __syncthreads();
  int rsub = wid*8 + (lane >> 3);          // row-within-32 for each staging issue
  int cbyte = (lane & 7) * 16;             // 16B column chunk within 128B row
  const char* xB    = (const char*)xbf;
  const char* eBase = (const char*)ewT + ((size_t)e << 21);  // e * 1024*1024*2B
  const char* srcA[4]; const char* srcB[4];
  #pragma unroll
  for (int i=0;i<4;i++){
    srcA[i] = xB    + ((size_t)tokS[i*32 + rsub] << 11) + cbyte;         // token row, 2KB stride
    srcB[i] = eBase + ((size_t)(ncol0 + i*32 + rsub) << 11) + cbyte;     // n row of ewT
  }
  v4f zero = {0.f,0.f,0.f,0.f};
  v4f acc[4][4];
  #pragma unroll
  for (int mi=0;mi<4;mi++)
    #pragma unroll
    for (int ni=0;ni<4;ni++) acc[mi][ni] = zero;
  int wr = wid >> 1, wc = wid & 1;
  int fr = lane & 15, fq = lane >> 4;
  unsigned Abase = (unsigned)((wr*64 + fr)*64 + fq*8);
  unsigned Bbase = (unsigned)((wc*64 + fr)*64 + fq*8);

  for (int kt=0; kt<16; ++kt){
    int koff = kt*128;                     // bytes: 64 bf16 per K-chunk
    #pragma unroll
    for (int i=0;i<4;i++)
      gload16(srcA[i] + koff, (char*)As + (i*32 + wid*8)*128);
    #pragma unroll
    for (int i=0;i<4;i++)
      gload16(srcB[i] + koff, (char*)Bs + (i*32 + wid*8)*128);
    __syncthreads();                       // drains vmcnt -> staged data visible
    #pragma unroll
    for (int kk=0;kk<2;kk++){
      v8s a[4], b[4];
      #pragma unroll
      for (int mi=0;mi<4;mi++) a[mi] = *(const v8s*)(As + Abase + mi*16*64 + kk*32);
      #pragma unroll
      for (int ni=0;ni<4;ni++) b[ni] = *(const v8s*)(Bs + Bbase + ni*16*64 + kk*32);
      #pragma unroll
      for (int mi=0;mi<4;mi++)
        #pragma unroll
        for (int ni=0;ni<4;ni++)
          acc[mi][ni] = __builtin_amdgcn_mfma_f32_16x16x32_bf16(a[mi], b[ni], acc[mi][ni], 0, 0, 0);
    }
    __syncthreads();                       // all waves done reading before next stage
  }
  // epilogue: Y[slot] = bf16( w * (acc + eb[e]) )
  #pragma unroll
  for (int ni=0;ni<4;ni++){
    int cg = ncol0 + wc*64 + ni*16 + fr;
    float ebv = eb[e*D_OUT + cg];
    #pragma unroll
    for (int mi=0;mi<4;mi++){
      int rb0 = wr*64 + mi*16 + fq*4;
      #pragma unroll
      for (int q=0;q<4;q++){
        int r = rb0 + q;
        float v = wS[r] * (acc[mi][ni][q] + ebv);
        Y[(size_t)(slot0 + r)*D_OUT + cg] = f2bf(v);
      }
    }
  }
}

// ---------------- kernel 5: combine out[t] = Y[slotA[t]] + Y[slotB[t]] ----------------
__global__ __launch_bounds__(256) void k_combine(
    const unsigned short* __restrict__ Y,
    const int* __restrict__ slotA, const int* __restrict__ slotB,
    float* __restrict__ out)
{
  int gid = blockIdx.x*256 + threadIdx.x;   // 1M threads, 8 cols each
  int t = gid >> 7;
  int c = (gid & 127) << 3;
  v8u a = *(const v8u*)(Y + (size_t)slotA[t]*D_OUT + c);
  v8u b = *(const v8u*)(Y + (size_t)slotB[t]*D_OUT + c);
  float4 o0, o1;
  o0.x = bf2f(a[0]) + bf2f(b[0]);
  o0.y = bf2f(a[1]) + bf2f(b[1]);
  o0.z = bf2f(a[2]) + bf2f(b[2]);
  o0.w = bf2f(a[3]) + bf2f(b[3]);
  o1.x = bf2f(a[4]) + bf2f(b[4]);
  o1.y = bf2f(a[5]) + bf2f(b[5]);
  o1.z = bf2f(a[6]) + bf2f(b[6]);
  o1.w = bf2f(a[7]) + bf2f(b[7]);
  *(float4*)(out + (size_t)t*D_OUT + c)     = o0;
  *(float4*)(out + (size_t)t*D_OUT + c + 4) = o1;
}

// ---------------- launch ----------------
extern "C" void kernel_launch(void* const* d_in, const int* in_sizes, int n_in,
                              void* d_out, int out_size, void* d_ws, size_t ws_size,
                              hipStream_t stream)
{
  const float* x   = (const float*)d_in[0];
  const float* rw1 = (const float*)d_in[1];
  const float* rb1 = (const float*)d_in[2];
  const float* rw2 = (const float*)d_in[3];
  const float* rb2 = (const float*)d_in[4];
  const float* ew  = (const float*)d_in[5];
  const float* eb  = (const float*)d_in[6];
  float* out = (float*)d_out;

  char* ws = (char*)d_ws;
  size_t o = 0;
  auto alloc = [&](size_t bytes)->char*{
    char* p = ws + o; o = (o + bytes + 255) & ~(size_t)255; return p;
  };
  unsigned short* xbf = (unsigned short*)alloc((size_t)B_TOK*D_IN*2);
  unsigned short* ewT = (unsigned short*)alloc((size_t)NEXP*D_IN*D_OUT*2);
  unsigned short* Y   = (unsigned short*)alloc((size_t)MAXSLOTS*D_OUT*2);
  int2*   tok_ids = (int2*)  alloc(B_TOK*sizeof(int2));
  float2* tok_w   = (float2*)alloc(B_TOK*sizeof(float2));
  int*    atok    = (int*)   alloc(MAXSLOTS*4);
  float*  aw      = (float*) alloc(MAXSLOTS*4);
  int*    slotA   = (int*)   alloc(B_TOK*4);
  int*    slotB   = (int*)   alloc(B_TOK*4);
  int2*   ttab    = (int2*)  alloc(256*sizeof(int2));
  int*    ntil    = (int*)   alloc(256);
  if (o > ws_size) return;  // ws too small: bail (will show as validation failure)

  k_cvt_ew <<<dim3(32,32,NEXP),  dim3(32,8),  0, stream>>>(ew, ewT);
  k_router <<<dim3(512),         dim3(256),   0, stream>>>(x, rw1, rb1, rw2, rb2, xbf, tok_ids, tok_w);
  k_dispatch<<<dim3(1),          dim3(1024),  0, stream>>>(tok_ids, tok_w, atok, aw, slotA, slotB, ttab, ntil);
  k_gemm   <<<dim3(MAXTILES,8),  dim3(256),   0, stream>>>(xbf, ewT, eb, atok, aw, ttab, ntil, Y);
  k_combine<<<dim3(4096),        dim3(256),   0, stream>>>(Y, slotA, slotB, out);
}

// Round 9
// 280.432 us; speedup vs baseline: 1.0438x; 1.0080x over previous
//
#include <hip/hip_runtime.h>

#define B_TOK   8192
#define D_IN    1024
#define D_OUT   1024
#define NEXP    8
#define RH      128
#define MAXTILES 136
#define MAXSLOTS (MAXTILES*128)

typedef __attribute__((ext_vector_type(8))) short v8s;
typedef __attribute__((ext_vector_type(8))) unsigned short v8u;
typedef __attribute__((ext_vector_type(4))) unsigned short v4u;
typedef __attribute__((ext_vector_type(4))) float v4f;

__device__ __forceinline__ unsigned short f2bf(float f){
  unsigned int u = __float_as_uint(f);
  u += 0x7fffu + ((u >> 16) & 1u);
  return (unsigned short)(u >> 16);
}
__device__ __forceinline__ float bf2f(unsigned short s){
  return __uint_as_float(((unsigned int)s) << 16);
}
// async global->LDS, 16B per lane. LDS dest must be wave-uniform base (+lane*16 implicit).
__device__ __forceinline__ void gload16(const void* g, void* l){
  __builtin_amdgcn_global_load_lds(
      (const __attribute__((address_space(1))) unsigned int*)g,
      (__attribute__((address_space(3))) unsigned int*)l, 16, 0, 0);
}

// ---------------- kernel 1: ew [e][k][n] fp32 -> ewT [e][n][k] bf16 ----------------
__global__ __launch_bounds__(256) void k_cvt_ew(const float* __restrict__ ew,
                                                unsigned short* __restrict__ ewT){
  __shared__ float tile[32][33];
  int tx = threadIdx.x, ty = threadIdx.y;
  int n0 = blockIdx.x*32, k0 = blockIdx.y*32, e = blockIdx.z;
  size_t ebase = (size_t)e << 20;                       // 1024*1024
  #pragma unroll
  for (int i=0;i<4;i++){
    int kl = ty*4+i;
    tile[kl][tx] = ew[ebase + (size_t)(k0+kl)*1024 + n0 + tx];
  }
  __syncthreads();
  #pragma unroll
  for (int i=0;i<4;i++){
    int nl = ty*4+i;
    ewT[ebase + (size_t)(n0+nl)*1024 + (k0 + tx)] = f2bf(tile[tx][nl]);
  }
}

// ---------------- kernel 2: router (fp32) + fused x->bf16 emission ----------------
// 512 blocks x 256 threads, 16 tokens/block, LDS ~51KB.
// Router MUST stay fp32: bf16 logits flip top-k for ~1e-3 tokens -> absmax fail.
// Lane mapping (per wave w of 4): rh0 = w*32 + (lane&15), rh1 = rh0+16,
// tokens g*4..g*4+3 where g = lane>>4. acc[4 tok][2 rh] per lane.
__global__ __launch_bounds__(256) void k_router(
    const float* __restrict__ x,  const float* __restrict__ rw1,
    const float* __restrict__ rb1,const float* __restrict__ rw2,
    const float* __restrict__ rb2,
    unsigned short* __restrict__ xbf,
    int2* __restrict__ tok_ids, float2* __restrict__ tok_w)
{
  __shared__ float xs [16*68];     // [tok][k] pad 68: b128-aligned, conflict-light
  __shared__ float ws [64*132];    // [k][rh] pad 132: scalar reads conflict-free
  __shared__ float hs [16*132];    // [tok][rh]
  __shared__ float r2s[RH*NEXP];   // [rh][e] natural rw2 layout
  __shared__ float ls [16*NEXP];
  int tid  = threadIdx.x;
  int lane = tid & 63, w = tid >> 6;
  int g    = lane >> 4;                 // token group 0..3
  int j    = lane & 15;
  int rh0  = w*32 + j, rh1 = rh0 + 16;
  int tok0 = blockIdx.x * 16;

  { // stage rw2 [128][8] = 1024 floats, 1 float4/thread
    *(float4*)(r2s + tid*4) = *(const float4*)(rw2 + tid*4);
  }
  float acc[4][2];
  #pragma unroll
  for (int i=0;i<4;i++){ acc[i][0]=0.f; acc[i][1]=0.f; }

  for (int slab=0; slab<16; ++slab){
    int k0 = slab*64;
    { // stage xs (16 tok x 64 k) + emit bf16 x. 1 float4/thread, coalesced.
      int t = tid >> 4, c4 = tid & 15;
      float4 v = *(const float4*)(x + (size_t)(tok0+t)*D_IN + k0 + c4*4);
      *(float4*)(xs + t*68 + c4*4) = v;
      v4u ub = { f2bf(v.x), f2bf(v.y), f2bf(v.z), f2bf(v.w) };
      *(v4u*)(xbf + (size_t)(tok0+t)*D_IN + k0 + c4*4) = ub;
    }
    #pragma unroll
    for (int i=0;i<8;i++){ // stage ws (64 k x 128 rh), natural, b128 coalesced
      int idx = tid + 256*i;
      int r = idx >> 5, c4 = (idx & 31)*4;
      *(float4*)(ws + r*132 + c4) = *(const float4*)(rw1 + (size_t)(k0+r)*RH + c4);
    }
    __syncthreads();
    #pragma unroll 4
    for (int k=0;k<64;k+=4){
      v4f xv[4];
      #pragma unroll
      for (int i=0;i<4;i++) xv[i] = *(v4f*)(xs + (g*4+i)*68 + k);   // broadcast in 16-lane groups
      #pragma unroll
      for (int kk=0;kk<4;kk++){
        float w0 = ws[(k+kk)*132 + rh0];
        float w1 = ws[(k+kk)*132 + rh1];
        #pragma unroll
        for (int i=0;i<4;i++){
          acc[i][0] += xv[i][kk] * w0;
          acc[i][1] += xv[i][kk] * w1;
        }
      }
    }
    __syncthreads();
  }
  // h = tanh(acc + rb1) -> hs
  {
    float b0 = rb1[rh0], b1 = rb1[rh1];
    #pragma unroll
    for (int i=0;i<4;i++){
      hs[(g*4+i)*132 + rh0] = tanhf(acc[i][0] + b0);
      hs[(g*4+i)*132 + rh1] = tanhf(acc[i][1] + b1);
    }
  }
  __syncthreads();
  // logits: 128 threads, one (token, expert) pair each
  if (tid < 16*NEXP){
    int t = tid >> 3, e = tid & 7;
    float l = rb2[e];
    #pragma unroll 4
    for (int r=0;r<RH;r++) l += hs[t*132 + r] * r2s[r*8 + e];
    ls[t*8 + e] = l;
  }
  __syncthreads();
  // softmax + stable top-2 + renorm weights: 16 threads, 8 elems each
  if (tid < 16){
    int t = tid;
    float l[NEXP];
    #pragma unroll
    for (int e=0;e<NEXP;e++) l[e] = ls[t*8 + e];
    float mx = l[0];
    #pragma unroll
    for (int e=1;e<NEXP;e++) mx = fmaxf(mx, l[e]);
    float p[NEXP], s = 0.f;
    #pragma unroll
    for (int e=0;e<NEXP;e++){ p[e] = expf(l[e]-mx); s += p[e]; }
    float inv = 1.f/s;
    #pragma unroll
    for (int e=0;e<NEXP;e++) p[e] *= inv;
    int bi = 0; float bv = p[0]; int si = -1; float sv = -1.f;
    #pragma unroll
    for (int e=1;e<NEXP;e++){
      if (p[e] > bv){ sv = bv; si = bi; bv = p[e]; bi = e; }
      else if (p[e] > sv){ sv = p[e]; si = e; }
    }
    // nws = softmax over the top-k prob VALUES, per reference
    float e1 = expf(sv - bv);
    float n0 = 1.f/(1.f + e1);
    float n1 = 1.f - n0;
    tok_ids[tok0 + t] = make_int2(bi, si);
    tok_w [tok0 + t] = make_float2(n0, n1);
  }
}

// ---------------- kernel 3: dispatch (single block) ----------------
__global__ __launch_bounds__(1024) void k_dispatch(
    const int2* __restrict__ tok_ids, const float2* __restrict__ tok_w,
    int* __restrict__ atok, float* __restrict__ aw,
    int* __restrict__ slotA, int* __restrict__ slotB,
    int2* __restrict__ ttab, int* __restrict__ ntiles)
{
  __shared__ int cnt[NEXP], base[NEXP], cur[NEXP];
  __shared__ int tot;
  int tid = threadIdx.x;
  if (tid < NEXP){ cnt[tid]=0; cur[tid]=0; }
  __syncthreads();
  for (int t=tid; t<B_TOK; t+=1024){
    int2 e = tok_ids[t];
    atomicAdd(&cnt[e.x],1);
    atomicAdd(&cnt[e.y],1);
  }
  __syncthreads();
  if (tid==0){
    int b=0, tt=0;
    for (int e=0;e<NEXP;e++){
      base[e]=b;
      int nt = (cnt[e]+127)>>7;
      for (int i=0;i<nt;i++) ttab[tt++] = make_int2(e, b + i*128);
      b += nt*128;
    }
    tot = b; *ntiles = tt;
  }
  __syncthreads();
  int tt_ = tot;
  for (int s=tid; s<tt_; s+=1024){ atok[s]=0; aw[s]=0.f; }  // padding: token 0, weight 0
  __syncthreads();
  for (int t=tid; t<B_TOK; t+=1024){
    int2 e = tok_ids[t]; float2 w = tok_w[t];
    int sA = base[e.x] + atomicAdd(&cur[e.x],1);
    atok[sA]=t; aw[sA]=w.x; slotA[t]=sA;
    int sB = base[e.y] + atomicAdd(&cur[e.y],1);
    atok[sB]=t; aw[sB]=w.y; slotB[t]=sB;
  }
}

// ---------------- kernel 4: grouped GEMM ----------------
// flat grid 1088 = 136 tiles x 8 nblocks. XCD chunk swizzle: XCD c (= bid%8)
// gets logicals [c*136,(c+1)*136) = 17 tiles x 8 nblocks -> A panels ~4.3MB +
// ~1 expert B panel 2MB ~ L2-resident per XCD.
// Pipeline: LDS double-buffer, stage(k+1) issued before compute(k), ONE
// __syncthreads per K-step (its vmcnt(0) drain completes the in-flight stage;
// buf^1's prior-iter reads are in registers before the barrier -> safe).
// LDS bank conflicts: [128][64]bf16 rows = 128B stride -> all 16 same-fq lanes
// on one bank quad (16-way). Fix: XOR chunk swizzle c ^= row&7, applied on the
// per-lane GLOBAL source (LDS dest stays linear, rule: both-sides-or-neither)
// and on the ds_read address.
__global__ __launch_bounds__(256) void k_gemm(
    const unsigned short* __restrict__ xbf, const unsigned short* __restrict__ ewT,
    const float* __restrict__ eb,
    const int* __restrict__ atok, const float* __restrict__ aw,
    const int2* __restrict__ ttab, const int* __restrict__ ntiles,
    unsigned short* __restrict__ Y)
{
  int bid = blockIdx.x;
  int logical = (bid & 7)*MAXTILES + (bid >> 3);   // bijective, 1088 = 8*136
  int tile = logical >> 3, nb = logical & 7;
  if (tile >= *ntiles) return;                      // whole block exits: no barrier hazard
  __shared__ __align__(16) unsigned short As[2][128*64];
  __shared__ __align__(16) unsigned short Bs[2][128*64];
  __shared__ int   tokS[128];
  __shared__ float wS[128];
  int tid = threadIdx.x;
  int lane = tid & 63, wid = tid >> 6;
  int2 tt = ttab[tile];
  int e = tt.x, slot0 = tt.y;
  int ncol0 = nb * 128;
  if (tid < 128){ tokS[tid] = atok[slot0 + tid]; wS[tid] = aw[slot0 + tid]; }
  __syncthreads();
  int rsub = wid*8 + (lane >> 3);          // row-within-32 for each staging issue
  // swizzled source chunk: row&7 == lane>>3 for all staged rows (row = i*32+wid*8+(lane>>3))
  int cbyte = ((lane & 7) ^ (lane >> 3)) * 16;
  const char* xB    = (const char*)xbf;
  const char* eBase = (const char*)ewT + ((size_t)e << 21);  // e * 1024*1024*2B
  const char* srcA[4]; const char* srcB[4];
  #pragma unroll
  for (int i=0;i<4;i++){
    srcA[i] = xB    + ((size_t)tokS[i*32 + rsub] << 11) + cbyte;         // token row, 2KB stride
    srcB[i] = eBase + ((size_t)(ncol0 + i*32 + rsub) << 11) + cbyte;     // n row of ewT
  }
  v4f zero = {0.f,0.f,0.f,0.f};
  v4f acc[4][4];
  #pragma unroll
  for (int mi=0;mi<4;mi++)
    #pragma unroll
    for (int ni=0;ni<4;ni++) acc[mi][ni] = zero;
  int wr = wid >> 1, wc = wid & 1;
  int fr = lane & 15, fq = lane >> 4;      // fq in 0..3
  // swizzled ds_read chunk offsets (shorts): chunk = (fq+4*kk) ^ (fr&7)
  int r7 = fr & 7;
  unsigned c0 = (unsigned)((fq       ^ r7) * 8);
  unsigned c1 = (unsigned)(((fq + 4) ^ r7) * 8);
  unsigned ArowBase = (unsigned)((wr*64 + fr)*64);
  unsigned BrowBase = (unsigned)((wc*64 + fr)*64);

  // prologue: stage K-chunk 0 into buf 0
  #pragma unroll
  for (int i=0;i<4;i++) gload16(srcA[i],       (char*)As[0] + (i*32 + wid*8)*128);
  #pragma unroll
  for (int i=0;i<4;i++) gload16(srcB[i],       (char*)Bs[0] + (i*32 + wid*8)*128);
  __syncthreads();                         // drains vmcnt -> buf0 visible

  for (int kt=0; kt<16; ++kt){
    int cur = kt & 1;
    if (kt < 15){                          // stage next chunk into the other buffer
      int koff = (kt+1)*128;
      #pragma unroll
      for (int i=0;i<4;i++) gload16(srcA[i] + koff, (char*)As[cur^1] + (i*32 + wid*8)*128);
      #pragma unroll
      for (int i=0;i<4;i++) gload16(srcB[i] + koff, (char*)Bs[cur^1] + (i*32 + wid*8)*128);
    }
    const unsigned short* Ab = As[cur];
    const unsigned short* Bb = Bs[cur];
    {
      v8s a[4], b[4];
      #pragma unroll
      for (int mi=0;mi<4;mi++) a[mi] = *(const v8s*)(Ab + ArowBase + mi*1024 + c0);
      #pragma unroll
      for (int ni=0;ni<4;ni++) b[ni] = *(const v8s*)(Bb + BrowBase + ni*1024 + c0);
      #pragma unroll
      for (int mi=0;mi<4;mi++)
        #pragma unroll
        for (int ni=0;ni<4;ni++)
          acc[mi][ni] = __builtin_amdgcn_mfma_f32_16x16x32_bf16(a[mi], b[ni], acc[mi][ni], 0, 0, 0);
    }
    {
      v8s a[4], b[4];
      #pragma unroll
      for (int mi=0;mi<4;mi++) a[mi] = *(const v8s*)(Ab + ArowBase + mi*1024 + c1);
      #pragma unroll
      for (int ni=0;ni<4;ni++) b[ni] = *(const v8s*)(Bb + BrowBase + ni*1024 + c1);
      #pragma unroll
      for (int mi=0;mi<4;mi++)
        #pragma unroll
        for (int ni=0;ni<4;ni++)
          acc[mi][ni] = __builtin_amdgcn_mfma_f32_16x16x32_bf16(a[mi], b[ni], acc[mi][ni], 0, 0, 0);
    }
    __syncthreads();   // drain: next-chunk stage complete; this buf's reads are in regs
  }
  // epilogue: Y[slot] = bf16( w * (acc + eb[e]) )
  #pragma unroll
  for (int ni=0;ni<4;ni++){
    int cg = ncol0 + wc*64 + ni*16 + fr;
    float ebv = eb[e*D_OUT + cg];
    #pragma unroll
    for (int mi=0;mi<4;mi++){
      int rb0 = wr*64 + mi*16 + fq*4;
      #pragma unroll
      for (int q=0;q<4;q++){
        int r = rb0 + q;
        float v = wS[r] * (acc[mi][ni][q] + ebv);
        Y[(size_t)(slot0 + r)*D_OUT + cg] = f2bf(v);
      }
    }
  }
}

// ---------------- kernel 5: combine out[t] = Y[slotA[t]] + Y[slotB[t]] ----------------
__global__ __launch_bounds__(256) void k_combine(
    const unsigned short* __restrict__ Y,
    const int* __restrict__ slotA, const int* __restrict__ slotB,
    float* __restrict__ out)
{
  int gid = blockIdx.x*256 + threadIdx.x;   // 1M threads, 8 cols each
  int t = gid >> 7;
  int c = (gid & 127) << 3;
  v8u a = *(const v8u*)(Y + (size_t)slotA[t]*D_OUT + c);
  v8u b = *(const v8u*)(Y + (size_t)slotB[t]*D_OUT + c);
  float4 o0, o1;
  o0.x = bf2f(a[0]) + bf2f(b[0]);
  o0.y = bf2f(a[1]) + bf2f(b[1]);
  o0.z = bf2f(a[2]) + bf2f(b[2]);
  o0.w = bf2f(a[3]) + bf2f(b[3]);
  o1.x = bf2f(a[4]) + bf2f(b[4]);
  o1.y = bf2f(a[5]) + bf2f(b[5]);
  o1.z = bf2f(a[6]) + bf2f(b[6]);
  o1.w = bf2f(a[7]) + bf2f(b[7]);
  *(float4*)(out + (size_t)t*D_OUT + c)     = o0;
  *(float4*)(out + (size_t)t*D_OUT + c + 4) = o1;
}

// ---------------- launch ----------------
extern "C" void kernel_launch(void* const* d_in, const int* in_sizes, int n_in,
                              void* d_out, int out_size, void* d_ws, size_t ws_size,
                              hipStream_t stream)
{
  const float* x   = (const float*)d_in[0];
  const float* rw1 = (const float*)d_in[1];
  const float* rb1 = (const float*)d_in[2];
  const float* rw2 = (const float*)d_in[3];
  const float* rb2 = (const float*)d_in[4];
  const float* ew  = (const float*)d_in[5];
  const float* eb  = (const float*)d_in[6];
  float* out = (float*)d_out;

  char* ws = (char*)d_ws;
  size_t o = 0;
  auto alloc = [&](size_t bytes)->char*{
    char* p = ws + o; o = (o + bytes + 255) & ~(size_t)255; return p;
  };
  unsigned short* xbf = (unsigned short*)alloc((size_t)B_TOK*D_IN*2);
  unsigned short* ewT = (unsigned short*)alloc((size_t)NEXP*D_IN*D_OUT*2);
  unsigned short* Y   = (unsigned short*)alloc((size_t)MAXSLOTS*D_OUT*2);
  int2*   tok_ids = (int2*)  alloc(B_TOK*sizeof(int2));
  float2* tok_w   = (float2*)alloc(B_TOK*sizeof(float2));
  int*    atok    = (int*)   alloc(MAXSLOTS*4);
  float*  aw      = (float*) alloc(MAXSLOTS*4);
  int*    slotA   = (int*)   alloc(B_TOK*4);
  int*    slotB   = (int*)   alloc(B_TOK*4);
  int2*   ttab    = (int2*)  alloc(256*sizeof(int2));
  int*    ntil    = (int*)   alloc(256);
  if (o > ws_size) return;  // ws too small: bail (will show as validation failure)

  k_cvt_ew <<<dim3(32,32,NEXP),  dim3(32,8),  0, stream>>>(ew, ewT);
  k_router <<<dim3(512),         dim3(256),   0, stream>>>(x, rw1, rb1, rw2, rb2, xbf, tok_ids, tok_w);
  k_dispatch<<<dim3(1),          dim3(1024),  0, stream>>>(tok_ids, tok_w, atok, aw, slotA, slotB, ttab, ntil);
  k_gemm   <<<dim3(MAXTILES*8),  dim3(256),   0, stream>>>(xbf, ewT, eb, atok, aw, ttab, ntil, Y);
  k_combine<<<dim3(4096),        dim3(256),   0, stream>>>(Y, slotA, slotB, out);
}